// Round 2
// 547.536 us; speedup vs baseline: 1.0168x; 1.0168x over previous
//
#include <hip/hip_runtime.h>
#include <hip/hip_bf16.h>

// Problem constants: B=4, S=1024, D=1024, H=4096, E=8, K=2
#define DIM_D 1024
#define DIM_H 4096
#define NUM_E 8
#define NUM_TOK 4096
#define MAXROWS 8320           // 2*NUM_TOK assignments + tile overrun pad

typedef __attribute__((ext_vector_type(8))) short short8;
typedef __attribute__((ext_vector_type(4))) float floatx4;

__device__ __forceinline__ unsigned short f2bf(float f) {
  union { float f; unsigned int u; } v; v.f = f;
  unsigned int r = v.u + 0x7fffu + ((v.u >> 16) & 1u);   // RNE
  return (unsigned short)(r >> 16);
}

__device__ __forceinline__ void async_copy16(const void* g, void* l) {
  __builtin_amdgcn_global_load_lds(
      (__attribute__((address_space(1))) unsigned int*)(g),
      (__attribute__((address_space(3))) unsigned int*)(l), 16, 0, 0);
}

// ------------- routing: histogram + scan + deterministic row ranks, one block -------------
// 256 threads x 16 tokens = 4096 tokens exactly.
__global__ __launch_bounds__(256) void route_scan(
    const int* __restrict__ assign, int* __restrict__ counts,
    int* __restrict__ offsets, int* __restrict__ tok2row) {
  __shared__ int hist[256][NUM_E];   // 8 KB
  __shared__ int base[NUM_E];
  const int tid = threadIdx.x;
  const int t0 = tid * 16;           // 16 tokens per thread
#pragma unroll
  for (int e = 0; e < NUM_E; e++) hist[tid][e] = 0;
  const int4* ap = (const int4*)(assign + t0 * 2);   // 32 ints = 8 int4
  // count (dedup within token)
  for (int i = 0; i < 8; i++) {
    int4 v = ap[i];
    hist[tid][v.x]++; if (v.y != v.x) hist[tid][v.y]++;
    hist[tid][v.z]++; if (v.w != v.z) hist[tid][v.w]++;
  }
  __syncthreads();
  // 8 serial exclusive scans over the 256 thread-counts
  if (tid < NUM_E) {
    int acc = 0;
    for (int i = 0; i < 256; i++) { int v = hist[i][tid]; hist[i][tid] = acc; acc += v; }
    base[tid] = acc;                 // per-expert total
  }
  __syncthreads();
  if (tid == 0) {
    int acc = 0;
    for (int e = 0; e < NUM_E; e++) {
      int tot = base[e];
      counts[e] = tot; offsets[e] = acc; base[e] = acc; acc += tot;
    }
  }
  __syncthreads();
#pragma unroll
  for (int e = 0; e < NUM_E; e++) hist[tid][e] += base[e];   // own row only
  // assign rows (same traversal order as the count phase)
  for (int i = 0; i < 8; i++) {
    int4 v = ap[i];
    int t = t0 + 2 * i;
    int4 o;
    o.x = hist[tid][v.x]++;
    o.y = (v.y != v.x) ? hist[tid][v.y]++ : -1;
    o.z = hist[tid][v.z]++;
    o.w = (v.w != v.z) ? hist[tid][v.w]++ : -1;
    *(int4*)(tok2row + 2 * t) = o;
  }
}

// ------------- gather: pure copy, fp32->bf16, one block per token -------------
__global__ void gather_x(const float* __restrict__ x, const int* __restrict__ tok2row,
                         unsigned short* __restrict__ Xg) {
  int t = blockIdx.x;
  int r0 = tok2row[2 * t], r1 = tok2row[2 * t + 1];
  const float4* xv = (const float4*)(x + (size_t)t * DIM_D);
  float4 v0 = xv[threadIdx.x * 2];
  float4 v1 = xv[threadIdx.x * 2 + 1];
  unsigned short h[8];
  h[0] = f2bf(v0.x); h[1] = f2bf(v0.y); h[2] = f2bf(v0.z); h[3] = f2bf(v0.w);
  h[4] = f2bf(v1.x); h[5] = f2bf(v1.y); h[6] = f2bf(v1.z); h[7] = f2bf(v1.w);
  uint4 pack = *(uint4*)h;
  *(uint4*)(Xg + (size_t)r0 * DIM_D + threadIdx.x * 8) = pack;
  if (r1 >= 0)
    *(uint4*)(Xg + (size_t)r1 * DIM_D + threadIdx.x * 8) = pack;
}

// ------------- weight transpose + cvt: 64x64 tiles, coalesced reads AND writes -------------
// z = e*2+which. which=0: W1 [D][H] -> W1t [H][D]; which=1: W2 [H][D] -> W2t [D][H]
// LDS swizzle: element (r,c) of the input tile lives at
//   tile[r*64 + ((c>>2) ^ (r>>3))*4 + (c&3)]
// phase 1: float4 writes -> 8 consecutive lanes hit 8 distinct bank-quads (conflict-free)
// phase 2: lane (s=tid&7, c=tid>>3) reads r=8s..8s+7 of output row c:
//   bank = ((ch^s)&7)*4 + (c&3) -> exactly 2 lanes/bank per wave (free),
//   then stores 16B at op[c*R + 8s] -> 8 lanes = 128B contiguous per output row.
__global__ __launch_bounds__(256) void transpose_cvt64(
    const float* __restrict__ W1, const float* __restrict__ W2,
    unsigned short* __restrict__ W1t, unsigned short* __restrict__ W2t) {
  __shared__ float tile[64 * 64];    // 16 KB
  const int z = blockIdx.y;
  const int e = z >> 1, which = z & 1;
  const int R = which ? DIM_H : DIM_D;
  const int C = which ? DIM_D : DIM_H;
  const int nbx = C / 64;
  const int bx = blockIdx.x % nbx;
  const int by = blockIdx.x / nbx;
  const float* ip = (which ? W2 : W1) + (size_t)e * R * C + (size_t)(by * 64) * C + bx * 64;
  unsigned short* op = (which ? W2t : W1t) + (size_t)e * R * C + (size_t)(bx * 64) * R + by * 64;
  const int tid = threadIdx.x;

  // phase 1: coalesced float4 reads; swizzled float4 LDS writes
  {
    int chunk = tid & 15;            // c-quad 0..15
    int rb = tid >> 4;               // 0..15
#pragma unroll
    for (int p = 0; p < 4; p++) {
      int r = rb + p * 16;
      float4 v = *(const float4*)(ip + (size_t)r * C + chunk * 4);
      int slot = chunk ^ (r >> 3);
      *(float4*)&tile[r * 64 + slot * 4] = v;
    }
  }
  __syncthreads();
  // phase 2: conflict-free strided reads, coalesced 16B stores
  {
    int s = tid & 7;                 // r-segment
    int c0 = tid >> 3;               // 0..31
#pragma unroll
    for (int i = 0; i < 2; i++) {
      int c = c0 + i * 32;
      int ch = c >> 2, cl = c & 3;
      int base = ((ch ^ s) * 4) + cl;    // constant over j (s == r>>3 for all j)
      unsigned short h[8];
#pragma unroll
      for (int j = 0; j < 8; j++) {
        int r = 8 * s + j;
        h[j] = f2bf(tile[r * 64 + base]);
      }
      *(uint4*)(op + (size_t)c * R + 8 * s) = *(const uint4*)h;
    }
  }
}

// ---------------- grouped GEMM, BK=64, XOR-swizzled LDS ----------------
// MODE 0: z=expert.            Hout[row,n] = bf16(relu(acc + bias[n]))
// MODE 1: z=e*2+half, split-K. Yout[half][row,n] = acc (+ bias if half==0)
template <int MODE, int KTOT>
__global__ __launch_bounds__(256) void moe_gemm(
    const unsigned short* __restrict__ Ain, const unsigned short* __restrict__ Bt,
    const float* __restrict__ bias, const int* __restrict__ counts,
    const int* __restrict__ offsets,
    unsigned short* __restrict__ Hout, float* __restrict__ Yout,
    int lda, int ldb, int N) {
  int e, half;
  if (MODE == 0) { e = blockIdx.z; half = 0; }
  else           { e = blockIdx.z >> 1; half = blockIdx.z & 1; }
  const int cnt = counts[e];
  int mt_, nt_;
  if (MODE == 0) {
    nt_ = (blockIdx.x & 7) | ((blockIdx.y & 3) << 3);
    mt_ = (blockIdx.x >> 3) | ((blockIdx.y >> 2) << 2);
  } else {
    nt_ = blockIdx.x; mt_ = blockIdx.y;
  }
  const int m0 = mt_ * 128;
  if (m0 >= cnt) return;
  const int n0 = nt_ * 128;
  const int rowbase = offsets[e];
  const unsigned short* A = Ain + (size_t)half * KTOT;

  __shared__ unsigned short sh[2 * 128 * 64];   // As | Bs, 32 KB
  unsigned short* As = sh;
  unsigned short* Bs = sh + 128 * 64;

  const int tid = threadIdx.x;
  const int w = tid >> 6;
  const int lane = tid & 63;
  const int l15 = lane & 15, l4 = lane >> 4;
  const int wm = w >> 1, wn = w & 1;
  const int lrow = lane >> 3, lslot = lane & 7;
  const int lchunk = lslot ^ lrow;   // XOR swizzle

  const unsigned short* gA[4]; const unsigned short* gB[4];
  void* dA[4]; void* dB[4];
  const unsigned short* Bbase = Bt + (size_t)e * N * ldb + (size_t)half * KTOT;
#pragma unroll
  for (int p = 0; p < 4; p++) {
    int rw = p * 32 + w * 8;
    gA[p] = A + (size_t)(rowbase + m0 + rw + lrow) * lda + lchunk * 8;
    gB[p] = Bbase + (size_t)(n0 + rw + lrow) * ldb + lchunk * 8;
    dA[p] = (char*)As + rw * 128;
    dB[p] = (char*)Bs + rw * 128;
  }

  floatx4 acc[4][4];
#pragma unroll
  for (int i = 0; i < 4; i++)
#pragma unroll
    for (int j = 0; j < 4; j++) acc[i][j] = (floatx4){0.f, 0.f, 0.f, 0.f};

  int arow[4], brow[4], sl[2];
  sl[0] = ((l4 + 0) ^ (l15 & 7)) * 8;
  sl[1] = ((l4 + 4) ^ (l15 & 7)) * 8;
#pragma unroll
  for (int mt = 0; mt < 4; mt++) arow[mt] = (wm * 64 + mt * 16 + l15) * 64;
#pragma unroll
  for (int nt = 0; nt < 4; nt++) brow[nt] = (wn * 64 + nt * 16 + l15) * 64;

  for (int k0 = 0; k0 < KTOT; k0 += 64) {
    __syncthreads();
#pragma unroll
    for (int p = 0; p < 4; p++) async_copy16(gA[p], dA[p]);
#pragma unroll
    for (int p = 0; p < 4; p++) async_copy16(gB[p], dB[p]);
#pragma unroll
    for (int p = 0; p < 4; p++) { gA[p] += 64; gB[p] += 64; }
    __syncthreads();
#pragma unroll
    for (int s = 0; s < 2; s++) {
      short8 a[4], b[4];
#pragma unroll
      for (int mt = 0; mt < 4; mt++) a[mt] = *(const short8*)(As + arow[mt] + sl[s]);
#pragma unroll
      for (int nt = 0; nt < 4; nt++) b[nt] = *(const short8*)(Bs + brow[nt] + sl[s]);
#pragma unroll
      for (int mt = 0; mt < 4; mt++)
#pragma unroll
        for (int nt = 0; nt < 4; nt++)
          acc[mt][nt] = __builtin_amdgcn_mfma_f32_16x16x32_bf16(a[mt], b[nt], acc[mt][nt], 0, 0, 0);
    }
  }

  // ---- epilogue: per-wave-private LDS transpose -> 16B vector stores ----
  __syncthreads();
  float* sbuf = (float*)sh + w * 1088;
  const bool addb = (MODE == 0) || (half == 0);
  const float* be = bias + (size_t)e * N + n0 + wn * 64;
  float* yplane = (MODE == 1) ? (Yout + (size_t)half * MAXROWS * N) : nullptr;
#pragma unroll
  for (int mt = 0; mt < 4; mt++) {
#pragma unroll
    for (int nt = 0; nt < 4; nt++) {
      float bv = addb ? be[nt * 16 + l15] : 0.f;
#pragma unroll
      for (int r = 0; r < 4; r++) {
        float v = acc[mt][nt][r] + bv;
        if (MODE == 0) v = fmaxf(v, 0.f);
        sbuf[(l4 * 4 + r) * 68 + nt * 16 + l15] = v;
      }
    }
    __asm__ __volatile__("s_waitcnt lgkmcnt(0)" ::: "memory");
#pragma unroll
    for (int pass = 0; pass < 4; pass++) {
      int row = pass * 4 + l4;
      int col4 = l15 * 4;
      int gm = m0 + wm * 64 + mt * 16 + row;
      float4 v = *(const float4*)&sbuf[row * 68 + col4];
      if (gm < cnt) {
        size_t off = (size_t)(rowbase + gm) * N + n0 + wn * 64 + col4;
        if (MODE == 0) {
          ushort4 h;
          h.x = f2bf(v.x); h.y = f2bf(v.y); h.z = f2bf(v.z); h.w = f2bf(v.w);
          *(ushort4*)(Hout + off) = h;
        } else {
          *(float4*)(yplane + off) = v;
        }
      }
    }
    __asm__ __volatile__("s_waitcnt lgkmcnt(0)" ::: "memory");
  }
}

// ------------- combine: out[t] = (sum over splitK halves and assigned rows)/k -------------
__global__ void combine_k(const float* __restrict__ Yg, const int* __restrict__ tok2row,
                          const int* __restrict__ kptr, float* __restrict__ out) {
  int t = blockIdx.x;
  int r0 = tok2row[2 * t], r1 = tok2row[2 * t + 1];
  float invk = 1.0f / (float)kptr[0];
  int d = threadIdx.x * 4;
  const size_t plane = (size_t)MAXROWS * DIM_D;
  float4 v = *(const float4*)(Yg + (size_t)r0 * DIM_D + d);
  float4 u = *(const float4*)(Yg + plane + (size_t)r0 * DIM_D + d);
  v.x += u.x; v.y += u.y; v.z += u.z; v.w += u.w;
  if (r1 >= 0) {
    float4 a = *(const float4*)(Yg + (size_t)r1 * DIM_D + d);
    float4 b = *(const float4*)(Yg + plane + (size_t)r1 * DIM_D + d);
    v.x += a.x + b.x; v.y += a.y + b.y; v.z += a.z + b.z; v.w += a.w + b.w;
  }
  float4 o; o.x = v.x * invk; o.y = v.y * invk; o.z = v.z * invk; o.w = v.w * invk;
  *(float4*)(out + (size_t)t * DIM_D + d) = o;
}

// ---------------- launch ----------------

extern "C" void kernel_launch(void* const* d_in, const int* in_sizes, int n_in,
                              void* d_out, int out_size, void* d_ws, size_t ws_size,
                              hipStream_t stream) {
  const float* x = (const float*)d_in[0];
  const float* W1 = (const float*)d_in[1];
  const float* b1 = (const float*)d_in[2];
  const float* W2 = (const float*)d_in[3];
  const float* b2 = (const float*)d_in[4];
  const int* assign = (const int*)d_in[5];
  const int* kptr = (const int*)d_in[6];
  float* out = (float*)d_out;

  char* p = (char*)d_ws;
  int* counts = (int*)p; p += 256;
  int* offsets = (int*)p; p += 256;
  int* tok2row = (int*)p; p += NUM_TOK * 2 * 4;                                // 32 KB
  unsigned short* W1t = (unsigned short*)p; p += (size_t)NUM_E * DIM_D * DIM_H * 2; // 64 MB (dead after GEMM1)
  unsigned short* Xg = (unsigned short*)p; p += (size_t)MAXROWS * DIM_D * 2;   // 17 MB (dead after GEMM1)
  unsigned short* Hg = (unsigned short*)p; p += (size_t)MAXROWS * DIM_H * 2;   // 68 MB
  unsigned short* W2t = (unsigned short*)p; p += (size_t)NUM_E * DIM_D * DIM_H * 2; // 64 MB
  // Yg (2 split-K fp32 planes, 68.2 MB) aliases dead W1t (67.1 MB) + head of Xg
  float* Yg = (float*)W1t;

  route_scan<<<1, 256, 0, stream>>>(assign, counts, offsets, tok2row);
  gather_x<<<NUM_TOK, 128, 0, stream>>>(x, tok2row, Xg);

  transpose_cvt64<<<dim3(1024, 16), 256, 0, stream>>>(W1, W2, W1t, W2t);

  // GEMM1: Hg = relu(Xg @ W1 + b1)   (K=1024, N=4096)
  moe_gemm<0, DIM_D><<<dim3(32, 32, NUM_E), 256, 0, stream>>>(
      Xg, W1t, b1, counts, offsets, Hg, nullptr, DIM_D, DIM_D, DIM_H);
  // GEMM2 split-K=2: Yg[half] = Hg[:, half] @ W2[half] (+ b2 on half 0)  (Khalf=2048, N=1024)
  moe_gemm<1, DIM_H / 2><<<dim3(8, 32, NUM_E * 2), 256, 0, stream>>>(
      Hg, W2t, b2, counts, offsets, nullptr, Yg, DIM_H, DIM_H, DIM_D);

  combine_k<<<NUM_TOK, 256, 0, stream>>>(Yg, tok2row, kptr, out);
}